// Round 6
// baseline (315.621 us; speedup 1.0000x reference)
//
#include <hip/hip_runtime.h>

// Capsule routing, split-pipeline version (round 6 = resubmit of round-5
// source; rounds 3 and 5 both died on GPU acquisition timeouts).
//   B=256, S=512, D=256, NC=16, DC=32, ROUTINGS=3
// Pipeline (6 dispatches, all on stream; ws carries intermediates):
//   k_colsum: partial colsums of U                    -> cpart[1024][256]
//   k_route(mode=0): v0 -> out1 -> wt1(bf16)          -> wt[256][16][256]
//   k_pass:  per 128-row tile: U->bf16 LDS, Y=U.wt^T (MFMA), softmax_n,
//            Vpart = C^T.U (MFMA)                     -> vpart[1024][16][256]
//   k_route(mode=1): V -> out2 -> wt2
//   k_pass
//   k_route(mode=1, final): V -> out3 -> d_out
// Squash is scale-invariant (eps negligible at these magnitudes), so the
// uniform-softmax 1/16 and colsum scaling are dropped.

#define DIN   256
#define OC    512
#define SROWS 512

typedef __attribute__((ext_vector_type(8))) __bf16 bf16x8;
typedef __attribute__((ext_vector_type(4))) float f32x4;
typedef __attribute__((ext_vector_type(4))) unsigned short u16x4;

__device__ __forceinline__ unsigned short f2bf(float f) {
  unsigned u = __float_as_uint(f);
  u += 0x7FFFu + ((u >> 16) & 1u);   // RNE
  return (unsigned short)(u >> 16);
}

// XOR swizzle on ushort index, flips bits 3-5, hashed so rows differing in
// bits 0-4 spread (fixes g-collision: s&7 alone is constant across g*8).
#define SWZ(r) ((((r) ^ ((r) >> 3)) & 7) << 3)

// ---------------------------------------------------------------- k_colsum
__global__ __launch_bounds__(256) void k_colsum(
    const float* __restrict__ Uall, float* __restrict__ cpart)
{
  __shared__ float sA[4][256];
  const int t = blockIdx.x, b = blockIdx.y;
  const int tid = threadIdx.x;
  const int c4 = tid & 63, rq = tid >> 6;
  const float4* g4 = (const float4*)(Uall + (size_t)b * (SROWS * DIN));
  const int R0 = t * 128;
  float4 a = {0.f, 0.f, 0.f, 0.f};
  #pragma unroll 8
  for (int k = 0; k < 32; ++k) {
    float4 v = g4[(R0 + rq + 4 * k) * 64 + c4];
    a.x += v.x; a.y += v.y; a.z += v.z; a.w += v.w;
  }
  *(float4*)&sA[rq][4 * c4] = a;
  __syncthreads();
  if (tid < 64) {
    float4 s = {0.f, 0.f, 0.f, 0.f};
    #pragma unroll
    for (int q = 0; q < 4; ++q) {
      float4 v = *(float4*)&sA[q][4 * tid];
      s.x += v.x; s.y += v.y; s.z += v.z; s.w += v.w;
    }
    *(float4*)&cpart[(size_t)(b * 4 + t) * 256 + 4 * tid] = s;
  }
}

// ---------------------------------------------------------------- k_route
// mode 0: src = cpart (broadcast v0 over n). mode 1: src = vpart.
// final: write out to d_out and stop; else compute wt (bf16) into ws.
__global__ __launch_bounds__(512) void k_route(
    const float* __restrict__ W, const float* __restrict__ src,
    unsigned short* __restrict__ wt, float* __restrict__ outF,
    int mode, int final_)
{
  __shared__ float sV[16 * 256];
  __shared__ float sP[2][512];
  __shared__ float sOut[512];
  const int b = blockIdx.x;
  const int tid = threadIdx.x;

  // --- A: fill sV[16][256]
  if (mode == 0) {
    if (tid < 256) {
      float v = 0.f;
      #pragma unroll
      for (int t = 0; t < 4; ++t) v += src[(size_t)(b * 4 + t) * 256 + tid];
      #pragma unroll
      for (int n = 0; n < 16; ++n) sV[n * 256 + tid] = v;
    }
  } else {
    #pragma unroll
    for (int qq = 0; qq < 2; ++qq) {
      const int q = 2 * tid + qq;   // float4 slot 0..1023
      f32x4 s = {0.f, 0.f, 0.f, 0.f};
      #pragma unroll
      for (int t = 0; t < 4; ++t)
        s += *(const f32x4*)&src[(size_t)(b * 4 + t) * 4096 + 4 * q];
      *(f32x4*)&sV[4 * q] = s;
    }
  }
  __syncthreads();

  // --- B: p[c] = sum_i V[n][i] * W[i][c]   (split i-range over 2 halves)
  {
    const int pair = tid & 255, half = tid >> 8;
    const int c0 = pair * 2, n = c0 >> 5;
    float p0 = 0.f, p1 = 0.f;
    const int i0 = half * 128;
    #pragma unroll 8
    for (int i = i0; i < i0 + 128; ++i) {
      const float2 wv = *(const float2*)&W[(size_t)i * OC + c0];
      const float x = sV[n * 256 + i];
      p0 = fmaf(wv.x, x, p0);
      p1 = fmaf(wv.y, x, p1);
    }
    sP[half][c0] = p0; sP[half][c0 + 1] = p1;
  }
  __syncthreads();

  // --- C: squash over each capsule's 32 dims
  {
    const float p = sP[0][tid] + sP[1][tid];
    float sq = p * p;
    #pragma unroll
    for (int off = 1; off < 32; off <<= 1) sq += __shfl_xor(sq, off);
    const float o = p * rsqrtf(sq + 1e-7f);
    if (final_) { outF[(size_t)b * 512 + tid] = o; return; }
    sOut[tid] = o;
  }
  __syncthreads();

  // --- D: wt[n][i] = sum_d W[i][n*32+d] * out[n*32+d]  (bf16 to ws)
  {
    const int f4i = tid & 127, rr = tid >> 7;   // f4i: 4-col group; rr 0..3
    const int n = f4i >> 3;
    const float4 ov = *(const float4*)&sOut[4 * f4i];
    #pragma unroll 4
    for (int it = 0; it < 64; ++it) {
      const int i = it * 4 + rr;
      const float4 wv = *(const float4*)&W[(size_t)i * OC + 4 * f4i];
      float p = wv.x * ov.x + wv.y * ov.y + wv.z * ov.z + wv.w * ov.w;
      p += __shfl_xor(p, 1);
      p += __shfl_xor(p, 2);
      p += __shfl_xor(p, 4);
      if ((tid & 7) == 0)
        wt[(size_t)b * 4096 + n * 256 + i] = f2bf(p);
    }
  }
}

// ---------------------------------------------------------------- k_pass
// One 128-row tile per block. LDS (dynamic, 77824 B):
//   sU  [128][256] ushort swz  @0      (64KB)
//   sWt [16][256]  ushort swz  @65536  (8KB)
//   sCT [16][128]  ushort swz  @73728  (4KB)
__global__ __launch_bounds__(512, 4) void k_pass(
    const float* __restrict__ Uall, const unsigned short* __restrict__ wt,
    float* __restrict__ vpart)
{
  extern __shared__ char smem[];
  unsigned short* sU  = (unsigned short*)smem;
  unsigned short* sWt = (unsigned short*)(smem + 65536);
  unsigned short* sCT = (unsigned short*)(smem + 73728);

  const int t = blockIdx.x, b = blockIdx.y;
  const int tid = threadIdx.x;
  const int w = tid >> 6, l = tid & 63;
  const int nr = l & 15, g = l >> 4;
  const float4* g4 = (const float4*)(Uall + (size_t)b * (SROWS * DIN));
  const int R0 = t * 128;

  // load wt tile (8KB): 512 threads x uint4 = 16 rows x 256 cols (BUGFIX
  // from round 4: old guard tid<256 left rows 8-15 uninitialized -> NaN)
  {
    const int n = tid >> 5, i0 = (tid & 31) * 8;
    const uint4 wv = *(const uint4*)&wt[(size_t)b * 4096 + n * 256 + i0];
    *(uint4*)&sWt[(n * 256 + i0) ^ SWZ(n)] = wv;
  }
  // stage U tile -> bf16 LDS
  #pragma unroll 4
  for (int k = 0; k < 16; ++k) {
    const int row = w * 16 + k;
    const float4 v = g4[(R0 + row) * 64 + l];
    u16x4 h;
    h[0] = f2bf(v.x); h[1] = f2bf(v.y); h[2] = f2bf(v.z); h[3] = f2bf(v.w);
    *(u16x4*)&sU[(row * 256 + 4 * l) ^ SWZ(row)] = h;
  }
  __syncthreads();

  // GEMM1: Y[16 rows (16w..)][16 n] = U . wt^T ; softmax over n; C^T -> sCT
  {
    f32x4 y = {0.f, 0.f, 0.f, 0.f};
    const int arow = 16 * w + nr;
    #pragma unroll
    for (int ks = 0; ks < 8; ++ks) {
      bf16x8 a  = *(const bf16x8*)&sU[(arow * 256 + ks * 32 + g * 8) ^ SWZ(arow)];
      bf16x8 bw = *(const bf16x8*)&sWt[(nr * 256 + ks * 32 + g * 8) ^ SWZ(nr)];
      y = __builtin_amdgcn_mfma_f32_16x16x32_bf16(a, bw, y, 0, 0, 0);
    }
    // no-max softmax over n (logits |y| <~ 5, fp32-safe)
    float e0 = __expf(y[0]), e1 = __expf(y[1]), e2 = __expf(y[2]), e3 = __expf(y[3]);
    float s0 = e0, s1 = e1, s2 = e2, s3 = e3;
    #pragma unroll
    for (int off = 1; off < 16; off <<= 1) {
      s0 += __shfl_xor(s0, off); s1 += __shfl_xor(s1, off);
      s2 += __shfl_xor(s2, off); s3 += __shfl_xor(s3, off);
    }
    u16x4 cw;
    cw[0] = f2bf(e0 / s0); cw[1] = f2bf(e1 / s1);
    cw[2] = f2bf(e2 / s2); cw[3] = f2bf(e3 / s3);
    // C^T[n=nr][s = 16w + 4g + r]
    *(u16x4*)&sCT[(nr * 128 + 16 * w + 4 * g) ^ SWZ(nr)] = cw;
  }
  __syncthreads();

  // GEMM2: V[16 n][256 i] = C^T[16x128] . U[128x256]; wave w does 2 i-tiles
  {
    const int icol0 = 32 * w + nr, icol1 = icol0 + 16;
    f32x4 v0 = {0.f, 0.f, 0.f, 0.f}, v1 = {0.f, 0.f, 0.f, 0.f};
    #pragma unroll
    for (int ks = 0; ks < 4; ++ks) {
      bf16x8 a = *(const bf16x8*)&sCT[(nr * 128 + ks * 32 + g * 8) ^ SWZ(nr)];
      bf16x8 b0, b1;
      #pragma unroll
      for (int j = 0; j < 8; ++j) {
        const int s = ks * 32 + g * 8 + j;
        b0[j] = __builtin_bit_cast(__bf16, sU[(s * 256 + icol0) ^ SWZ(s)]);
        b1[j] = __builtin_bit_cast(__bf16, sU[(s * 256 + icol1) ^ SWZ(s)]);
      }
      v0 = __builtin_amdgcn_mfma_f32_16x16x32_bf16(a, b0, v0, 0, 0, 0);
      v1 = __builtin_amdgcn_mfma_f32_16x16x32_bf16(a, b1, v1, 0, 0, 0);
    }
    float* vp = vpart + (size_t)(b * 4 + t) * 4096;
    #pragma unroll
    for (int r = 0; r < 4; ++r) {
      const int n = 4 * g + r;
      vp[n * 256 + icol0] = v0[r];
      vp[n * 256 + icol1] = v1[r];
    }
  }
}

// ------------------------------------------------------- fallback (round 1)
__global__ __launch_bounds__(1024) void caps_fused(
    const float* __restrict__ Uall, const float* __restrict__ Wg,
    float* __restrict__ outp)
{
  __shared__ __align__(16) unsigned short sU16[64 * 256];
  __shared__ __align__(16) unsigned short sWt16[16 * 256];
  __shared__ __align__(16) unsigned short sCT16[16 * 64];
  __shared__ __align__(16) float sV[16 * 256];
  __shared__ __align__(16) float sOut[512];
  float* sSS = (float*)sCT16;

  const int tid = threadIdx.x;
  const int w = tid >> 6, l = tid & 63;
  const int b = blockIdx.x;
  const float* U = Uall + (size_t)b * (SROWS * DIN);
  const float4* g4 = (const float4*)U;

  {
    float4 a = make_float4(0.f, 0.f, 0.f, 0.f);
    const int base = (w * 32) * 64 + l;
    #pragma unroll 8
    for (int r = 0; r < 32; ++r) {
      float4 v = g4[base + r * 64];
      a.x += v.x; a.y += v.y; a.z += v.z; a.w += v.w;
    }
    *(float4*)&sV[w * 256 + 4 * l] = a;
  }
  __syncthreads();
  if (tid < 256) {
    float s = 0.f;
    #pragma unroll
    for (int q = 0; q < 16; ++q) s += sV[q * 256 + tid];
    sSS[tid] = s * (1.0f / 16.0f);
  }
  __syncthreads();

  auto outCompute = [&](int mode) {
    if (tid < 512) {
      const int c = tid, n = c >> 5;
      float p0 = 0.f, p1 = 0.f, p2 = 0.f, p3 = 0.f;
      #pragma unroll 4
      for (int i = 0; i < 256; i += 4) {
        float x0 = mode ? sV[n * 256 + i + 0] : sSS[i + 0];
        float x1 = mode ? sV[n * 256 + i + 1] : sSS[i + 1];
        float x2 = mode ? sV[n * 256 + i + 2] : sSS[i + 2];
        float x3 = mode ? sV[n * 256 + i + 3] : sSS[i + 3];
        p0 = fmaf(Wg[(i + 0) * OC + c], x0, p0);
        p1 = fmaf(Wg[(i + 1) * OC + c], x1, p1);
        p2 = fmaf(Wg[(i + 2) * OC + c], x2, p2);
        p3 = fmaf(Wg[(i + 3) * OC + c], x3, p3);
      }
      float p = (p0 + p1) + (p2 + p3);
      float sq = p * p;
      #pragma unroll
      for (int off = 1; off < 32; off <<= 1) sq += __shfl_xor(sq, off);
      sOut[c] = p * rsqrtf(sq + 1e-7f);
    }
    __syncthreads();
  };

  auto wtCompute = [&]() {
    const int f4 = tid & 127;
    const int rr = tid >> 7;
    const float4 ov = *(const float4*)&sOut[4 * f4];
    #pragma unroll 4
    for (int it = 0; it < 32; ++it) {
      const int i = it * 8 + rr;
      const float4 wv = *(const float4*)&Wg[i * OC + 4 * f4];
      float p = wv.x * ov.x + wv.y * ov.y + wv.z * ov.z + wv.w * ov.w;
      p += __shfl_xor(p, 1);
      p += __shfl_xor(p, 2);
      p += __shfl_xor(p, 4);
      if ((f4 & 7) == 0) {
        const int n = f4 >> 3;
        sWt16[(n * 256 + i) ^ ((n & 7) << 3)] = f2bf(p);
      }
    }
    __syncthreads();
  };

  auto stage = [&](const float4* pre) {
    #pragma unroll
    for (int k = 0; k < 4; ++k) {
      const int s = w + 16 * k;
      u16x4 h;
      h[0] = f2bf(pre[k].x); h[1] = f2bf(pre[k].y);
      h[2] = f2bf(pre[k].z); h[3] = f2bf(pre[k].w);
      *(u16x4*)&sU16[(s * 256 + 4 * l) ^ ((s & 7) << 3)] = h;
    }
  };

  auto pass = [&]() {
    f32x4 vacc = {0.f, 0.f, 0.f, 0.f};
    const int nr = l & 15;
    const int grp = l >> 4;
    {
      float4 pre[4];
      #pragma unroll
      for (int k = 0; k < 4; ++k) pre[k] = g4[(w + 16 * k) * 64 + l];
      stage(pre);
    }
    __syncthreads();
    for (int chunk = 0; chunk < 8; ++chunk) {
      float4 nxt[4];
      if (chunk < 7) {
        #pragma unroll
        for (int k = 0; k < 4; ++k)
          nxt[k] = g4[((chunk + 1) * 64 + w + 16 * k) * 64 + l];
      }
      if (w < 4) {
        f32x4 y = {0.f, 0.f, 0.f, 0.f};
        const int arow = 16 * w + nr;
        #pragma unroll
        for (int ks = 0; ks < 8; ++ks) {
          bf16x8 a = *(const bf16x8*)&sU16[(arow * 256 + ks * 32 + grp * 8) ^ ((arow & 7) << 3)];
          bf16x8 bw = *(const bf16x8*)&sWt16[(nr * 256 + ks * 32 + grp * 8) ^ ((nr & 7) << 3)];
          y = __builtin_amdgcn_mfma_f32_16x16x32_bf16(a, bw, y, 0, 0, 0);
        }
        float e0 = __expf(y[0]), e1 = __expf(y[1]), e2 = __expf(y[2]), e3 = __expf(y[3]);
        float s0 = e0, s1 = e1, s2 = e2, s3 = e3;
        #pragma unroll
        for (int off = 1; off < 16; off <<= 1) {
          s0 += __shfl_xor(s0, off); s1 += __shfl_xor(s1, off);
          s2 += __shfl_xor(s2, off); s3 += __shfl_xor(s3, off);
        }
        u16x4 cw;
        cw[0] = f2bf(e0 / s0); cw[1] = f2bf(e1 / s1);
        cw[2] = f2bf(e2 / s2); cw[3] = f2bf(e3 / s3);
        *(u16x4*)&sCT16[(nr * 64 + 16 * w + 4 * grp) ^ ((nr & 7) << 3)] = cw;
      }
      __syncthreads();
      {
        const int icol = 16 * w + nr;
        #pragma unroll
        for (int ks = 0; ks < 2; ++ks) {
          bf16x8 a = *(const bf16x8*)&sCT16[(nr * 64 + ks * 32 + grp * 8) ^ ((nr & 7) << 3)];
          bf16x8 bb;
          const int s0b = ks * 32 + grp * 8;
          #pragma unroll
          for (int j = 0; j < 8; ++j) {
            unsigned short v = sU16[((s0b + j) * 256 + icol) ^ (j << 3)];
            bb[j] = __builtin_bit_cast(__bf16, v);
          }
          vacc = __builtin_amdgcn_mfma_f32_16x16x32_bf16(a, bb, vacc, 0, 0, 0);
        }
      }
      __syncthreads();
      if (chunk < 7) stage(nxt);
      __syncthreads();
    }
    #pragma unroll
    for (int r = 0; r < 4; ++r) sV[(grp * 4 + r) * 256 + 16 * w + nr] = vacc[r];
    __syncthreads();
  };

  outCompute(0);
  wtCompute();
  pass();
  outCompute(1);
  wtCompute();
  pass();
  outCompute(1);

  if (tid < 512) outp[(size_t)b * 512 + tid] = sOut[tid];
}

// ---------------------------------------------------------------- launch
extern "C" void kernel_launch(void* const* d_in, const int* in_sizes, int n_in,
                              void* d_out, int out_size, void* d_ws, size_t ws_size,
                              hipStream_t stream) {
  const float* U = (const float*)d_in[0];
  const float* W = (const float*)d_in[1];
  float* out = (float*)d_out;

  const size_t WT_OFF = 0;                 // 2 MB  bf16 wt [256][16][256]
  const size_t CP_OFF = 2u * 1024 * 1024;  // 1 MB  cpart [1024][256]
  const size_t VP_OFF = 3u * 1024 * 1024;  // 16 MB vpart [1024][16][256]
  const size_t NEED   = VP_OFF + 16u * 1024 * 1024;

  if (ws_size < NEED) {
    caps_fused<<<dim3(256), dim3(1024), 0, stream>>>(U, W, out);
    return;
  }
  unsigned short* wt = (unsigned short*)((char*)d_ws + WT_OFF);
  float* cpart = (float*)((char*)d_ws + CP_OFF);
  float* vpart = (float*)((char*)d_ws + VP_OFF);

  hipFuncSetAttribute(reinterpret_cast<const void*>(k_pass),
                      hipFuncAttributeMaxDynamicSharedMemorySize, 77824);

  k_colsum<<<dim3(4, 256), 256, 0, stream>>>(U, cpart);
  k_route<<<256, 512, 0, stream>>>(W, cpart, wt, out, 0, 0);
  k_pass<<<dim3(4, 256), 512, 77824, stream>>>(U, wt, vpart);
  k_route<<<256, 512, 0, stream>>>(W, vpart, wt, out, 1, 0);
  k_pass<<<dim3(4, 256), 512, 77824, stream>>>(U, wt, vpart);
  k_route<<<256, 512, 0, stream>>>(W, vpart, wt, out, 1, 1);
}

// Round 7
// 302.637 us; speedup vs baseline: 1.0429x; 1.0429x over previous
//
#include <hip/hip_runtime.h>

// Capsule routing, split pipeline v2 (round 7): U converted to bf16 ONCE.
//   B=256, S=512, D=256, NC=16, DC=32, ROUTINGS=3
// Pipeline (6 dispatches; ws carries intermediates):
//   k_cvt:   U fp32 -> Ub bf16 (64MB, L3-resident) + partial colsums
//   k_route(mode=0): v0 -> out1 -> wt1(bf16)
//   k_pass:  per 128-row tile: Ub -> LDS (uint4 copies), Y=U.wt^T (MFMA),
//            softmax_n, Vpart = C^T.U (MFMA)
//   k_route(mode=1): V -> out2 -> wt2
//   k_pass
//   k_route(mode=1, final): V -> out3 -> d_out
// Squash is scale-invariant, so uniform-softmax 1/16 and colsum scale drop.

#define DIN   256
#define OC    512
#define SROWS 512

typedef __attribute__((ext_vector_type(8))) __bf16 bf16x8;
typedef __attribute__((ext_vector_type(4))) float f32x4;
typedef __attribute__((ext_vector_type(4))) unsigned short u16x4;

__device__ __forceinline__ unsigned short f2bf(float f) {
  unsigned u = __float_as_uint(f);
  u += 0x7FFFu + ((u >> 16) & 1u);   // RNE
  return (unsigned short)(u >> 16);
}

// XOR swizzle on ushort index: flips bits 3-5 (16B-block index bits 0-2),
// hashed over row bits so both 8-row groups and 64-row strides spread.
#define SWZ(r) ((((r) ^ ((r) >> 3)) & 7) << 3)

// ---------------------------------------------------------------- k_cvt
// Reads U fp32, writes bf16 copy + per-tile column partial sums.
__global__ __launch_bounds__(256) void k_cvt(
    const float* __restrict__ Uall, float* __restrict__ cpart,
    unsigned short* __restrict__ Ub)
{
  __shared__ float sA[4][256];
  const int t = blockIdx.x, b = blockIdx.y;
  const int tid = threadIdx.x;
  const int c4 = tid & 63, rq = tid >> 6;
  const float4* g4 = (const float4*)(Uall + (size_t)b * (SROWS * DIN));
  unsigned short* ub = Ub + (size_t)b * (SROWS * DIN);
  const int R0 = t * 128;
  float4 a = {0.f, 0.f, 0.f, 0.f};
  #pragma unroll 8
  for (int k = 0; k < 32; ++k) {
    const int row = R0 + rq + 4 * k;
    float4 v = g4[row * 64 + c4];
    u16x4 h;
    h[0] = f2bf(v.x); h[1] = f2bf(v.y); h[2] = f2bf(v.z); h[3] = f2bf(v.w);
    *(u16x4*)&ub[(size_t)row * 256 + 4 * c4] = h;
    a.x += v.x; a.y += v.y; a.z += v.z; a.w += v.w;
  }
  *(float4*)&sA[rq][4 * c4] = a;
  __syncthreads();
  if (tid < 64) {
    float4 s = {0.f, 0.f, 0.f, 0.f};
    #pragma unroll
    for (int q = 0; q < 4; ++q) {
      float4 v = *(float4*)&sA[q][4 * tid];
      s.x += v.x; s.y += v.y; s.z += v.z; s.w += v.w;
    }
    *(float4*)&cpart[(size_t)(b * 4 + t) * 256 + 4 * tid] = s;
  }
}

// ---------------------------------------------------------------- k_route
// mode 0: src = cpart (broadcast v0 over n). mode 1: src = vpart.
// final: write out to d_out and stop; else compute wt (bf16) into ws.
__global__ __launch_bounds__(512) void k_route(
    const float* __restrict__ W, const float* __restrict__ src,
    unsigned short* __restrict__ wt, float* __restrict__ outF,
    int mode, int final_)
{
  __shared__ float sV[16 * 256];
  __shared__ float sP[2][512];
  __shared__ float sOut[512];
  const int b = blockIdx.x;
  const int tid = threadIdx.x;

  // --- A: fill sV[16][256]
  if (mode == 0) {
    if (tid < 256) {
      float v = 0.f;
      #pragma unroll
      for (int t = 0; t < 4; ++t) v += src[(size_t)(b * 4 + t) * 256 + tid];
      #pragma unroll
      for (int n = 0; n < 16; ++n) sV[n * 256 + tid] = v;
    }
  } else {
    #pragma unroll
    for (int qq = 0; qq < 2; ++qq) {
      const int q = 2 * tid + qq;   // float4 slot 0..1023
      f32x4 s = {0.f, 0.f, 0.f, 0.f};
      #pragma unroll
      for (int t = 0; t < 4; ++t)
        s += *(const f32x4*)&src[(size_t)(b * 4 + t) * 4096 + 4 * q];
      *(f32x4*)&sV[4 * q] = s;
    }
  }
  __syncthreads();

  // --- B: p[c] = sum_i V[n][i] * W[i][c]   (i-range split over 2 halves)
  {
    const int pair = tid & 255, half = tid >> 8;
    const int c0 = pair * 2, n = c0 >> 5;
    float p0 = 0.f, p1 = 0.f;
    const int i0 = half * 128;
    #pragma unroll 8
    for (int i = i0; i < i0 + 128; ++i) {
      const float2 wv = *(const float2*)&W[(size_t)i * OC + c0];
      const float x = sV[n * 256 + i];
      p0 = fmaf(wv.x, x, p0);
      p1 = fmaf(wv.y, x, p1);
    }
    sP[half][c0] = p0; sP[half][c0 + 1] = p1;
  }
  __syncthreads();

  // --- C: squash over each capsule's 32 dims
  {
    const float p = sP[0][tid] + sP[1][tid];
    float sq = p * p;
    #pragma unroll
    for (int off = 1; off < 32; off <<= 1) sq += __shfl_xor(sq, off);
    const float o = p * rsqrtf(sq + 1e-7f);
    if (final_) { outF[(size_t)b * 512 + tid] = o; return; }
    sOut[tid] = o;
  }
  __syncthreads();

  // --- D: wt[n][i] = sum_d W[i][n*32+d] * out[n*32+d]  (bf16 to ws)
  {
    const int f4i = tid & 127, rr = tid >> 7;
    const int n = f4i >> 3;
    const float4 ov = *(const float4*)&sOut[4 * f4i];
    #pragma unroll 4
    for (int it = 0; it < 64; ++it) {
      const int i = it * 4 + rr;
      const float4 wv = *(const float4*)&W[(size_t)i * OC + 4 * f4i];
      float p = wv.x * ov.x + wv.y * ov.y + wv.z * ov.z + wv.w * ov.w;
      p += __shfl_xor(p, 1);
      p += __shfl_xor(p, 2);
      p += __shfl_xor(p, 4);
      if ((tid & 7) == 0)
        wt[(size_t)b * 4096 + n * 256 + i] = f2bf(p);
    }
  }
}

// ---------------------------------------------------------------- k_pass
// One 128-row tile per block, input already bf16. LDS (dynamic, 77824 B):
//   sU  [128][256] ushort swz  @0      (64KB)
//   sWt [16][256]  ushort swz  @65536  (8KB)
//   sCT [16][128]  ushort swz  @73728  (4KB)
__global__ __launch_bounds__(512, 4) void k_pass(
    const unsigned short* __restrict__ Ub, const unsigned short* __restrict__ wt,
    float* __restrict__ vpart)
{
  extern __shared__ char smem[];
  unsigned short* sU  = (unsigned short*)smem;
  unsigned short* sWt = (unsigned short*)(smem + 65536);
  unsigned short* sCT = (unsigned short*)(smem + 73728);

  const int t = blockIdx.x, b = blockIdx.y;
  const int tid = threadIdx.x;
  const int w = tid >> 6, l = tid & 63;
  const int nr = l & 15, g = l >> 4;
  const unsigned short* ub = Ub + (size_t)b * (SROWS * DIN);
  const int R0 = t * 128;

  // load wt tile (8KB): 512 threads x uint4 = 16 rows x 256 cols
  {
    const int n = tid >> 5, i0 = (tid & 31) * 8;
    const uint4 wv = *(const uint4*)&wt[(size_t)b * 4096 + n * 256 + i0];
    *(uint4*)&sWt[(n * 256 + i0) ^ SWZ(n)] = wv;
  }
  // stage bf16 U tile -> LDS: pure uint4 copies (no conversion)
  {
    const int col8 = (tid & 31) * 8;
    const int r0 = tid >> 5;          // 0..15
    #pragma unroll
    for (int k = 0; k < 8; ++k) {
      const int row = r0 + 16 * k;    // 0..127
      const uint4 v = *(const uint4*)&ub[(size_t)(R0 + row) * 256 + col8];
      *(uint4*)&sU[(row * 256 + col8) ^ SWZ(row)] = v;
    }
  }
  __syncthreads();

  // GEMM1: Y[16 rows (16w..)][16 n] = U . wt^T ; softmax over n; C^T -> sCT
  {
    f32x4 y = {0.f, 0.f, 0.f, 0.f};
    const int arow = 16 * w + nr;
    #pragma unroll
    for (int ks = 0; ks < 8; ++ks) {
      bf16x8 a  = *(const bf16x8*)&sU[(arow * 256 + ks * 32 + g * 8) ^ SWZ(arow)];
      bf16x8 bw = *(const bf16x8*)&sWt[(nr * 256 + ks * 32 + g * 8) ^ SWZ(nr)];
      y = __builtin_amdgcn_mfma_f32_16x16x32_bf16(a, bw, y, 0, 0, 0);
    }
    // no-max softmax over n (logits small, fp32-safe)
    float e0 = __expf(y[0]), e1 = __expf(y[1]), e2 = __expf(y[2]), e3 = __expf(y[3]);
    float s0 = e0, s1 = e1, s2 = e2, s3 = e3;
    #pragma unroll
    for (int off = 1; off < 16; off <<= 1) {
      s0 += __shfl_xor(s0, off); s1 += __shfl_xor(s1, off);
      s2 += __shfl_xor(s2, off); s3 += __shfl_xor(s3, off);
    }
    u16x4 cw;
    cw[0] = f2bf(e0 / s0); cw[1] = f2bf(e1 / s1);
    cw[2] = f2bf(e2 / s2); cw[3] = f2bf(e3 / s3);
    // C^T[n=nr][s = 16w + 4g + r]
    *(u16x4*)&sCT[(nr * 128 + 16 * w + 4 * g) ^ SWZ(nr)] = cw;
  }
  __syncthreads();

  // GEMM2: V[16 n][256 i] = C^T[16x128] . U[128x256]; wave w does 2 i-tiles
  {
    const int icol0 = 32 * w + nr, icol1 = icol0 + 16;
    f32x4 v0 = {0.f, 0.f, 0.f, 0.f}, v1 = {0.f, 0.f, 0.f, 0.f};
    #pragma unroll
    for (int ks = 0; ks < 4; ++ks) {
      bf16x8 a = *(const bf16x8*)&sCT[(nr * 128 + ks * 32 + g * 8) ^ SWZ(nr)];
      bf16x8 b0, b1;
      #pragma unroll
      for (int j = 0; j < 8; ++j) {
        const int s = ks * 32 + g * 8 + j;
        b0[j] = __builtin_bit_cast(__bf16, sU[(s * 256 + icol0) ^ SWZ(s)]);
        b1[j] = __builtin_bit_cast(__bf16, sU[(s * 256 + icol1) ^ SWZ(s)]);
      }
      v0 = __builtin_amdgcn_mfma_f32_16x16x32_bf16(a, b0, v0, 0, 0, 0);
      v1 = __builtin_amdgcn_mfma_f32_16x16x32_bf16(a, b1, v1, 0, 0, 0);
    }
    float* vp = vpart + (size_t)(b * 4 + t) * 4096;
    #pragma unroll
    for (int r = 0; r < 4; ++r) {
      const int n = 4 * g + r;
      vp[n * 256 + icol0] = v0[r];
      vp[n * 256 + icol1] = v1[r];
    }
  }
}

// ------------------------------------------------------- fallback (round 1)
__global__ __launch_bounds__(1024) void caps_fused(
    const float* __restrict__ Uall, const float* __restrict__ Wg,
    float* __restrict__ outp)
{
  __shared__ __align__(16) unsigned short sU16[64 * 256];
  __shared__ __align__(16) unsigned short sWt16[16 * 256];
  __shared__ __align__(16) unsigned short sCT16[16 * 64];
  __shared__ __align__(16) float sV[16 * 256];
  __shared__ __align__(16) float sOut[512];
  float* sSS = (float*)sCT16;

  const int tid = threadIdx.x;
  const int w = tid >> 6, l = tid & 63;
  const int b = blockIdx.x;
  const float* U = Uall + (size_t)b * (SROWS * DIN);
  const float4* g4 = (const float4*)U;

  {
    float4 a = make_float4(0.f, 0.f, 0.f, 0.f);
    const int base = (w * 32) * 64 + l;
    #pragma unroll 8
    for (int r = 0; r < 32; ++r) {
      float4 v = g4[base + r * 64];
      a.x += v.x; a.y += v.y; a.z += v.z; a.w += v.w;
    }
    *(float4*)&sV[w * 256 + 4 * l] = a;
  }
  __syncthreads();
  if (tid < 256) {
    float s = 0.f;
    #pragma unroll
    for (int q = 0; q < 16; ++q) s += sV[q * 256 + tid];
    sSS[tid] = s * (1.0f / 16.0f);
  }
  __syncthreads();

  auto outCompute = [&](int mode) {
    if (tid < 512) {
      const int c = tid, n = c >> 5;
      float p0 = 0.f, p1 = 0.f, p2 = 0.f, p3 = 0.f;
      #pragma unroll 4
      for (int i = 0; i < 256; i += 4) {
        float x0 = mode ? sV[n * 256 + i + 0] : sSS[i + 0];
        float x1 = mode ? sV[n * 256 + i + 1] : sSS[i + 1];
        float x2 = mode ? sV[n * 256 + i + 2] : sSS[i + 2];
        float x3 = mode ? sV[n * 256 + i + 3] : sSS[i + 3];
        p0 = fmaf(Wg[(i + 0) * OC + c], x0, p0);
        p1 = fmaf(Wg[(i + 1) * OC + c], x1, p1);
        p2 = fmaf(Wg[(i + 2) * OC + c], x2, p2);
        p3 = fmaf(Wg[(i + 3) * OC + c], x3, p3);
      }
      float p = (p0 + p1) + (p2 + p3);
      float sq = p * p;
      #pragma unroll
      for (int off = 1; off < 32; off <<= 1) sq += __shfl_xor(sq, off);
      sOut[c] = p * rsqrtf(sq + 1e-7f);
    }
    __syncthreads();
  };

  auto wtCompute = [&]() {
    const int f4 = tid & 127;
    const int rr = tid >> 7;
    const float4 ov = *(const float4*)&sOut[4 * f4];
    #pragma unroll 4
    for (int it = 0; it < 32; ++it) {
      const int i = it * 8 + rr;
      const float4 wv = *(const float4*)&Wg[i * OC + 4 * f4];
      float p = wv.x * ov.x + wv.y * ov.y + wv.z * ov.z + wv.w * ov.w;
      p += __shfl_xor(p, 1);
      p += __shfl_xor(p, 2);
      p += __shfl_xor(p, 4);
      if ((f4 & 7) == 0) {
        const int n = f4 >> 3;
        sWt16[(n * 256 + i) ^ ((n & 7) << 3)] = f2bf(p);
      }
    }
    __syncthreads();
  };

  auto stage = [&](const float4* pre) {
    #pragma unroll
    for (int k = 0; k < 4; ++k) {
      const int s = w + 16 * k;
      u16x4 h;
      h[0] = f2bf(pre[k].x); h[1] = f2bf(pre[k].y);
      h[2] = f2bf(pre[k].z); h[3] = f2bf(pre[k].w);
      *(u16x4*)&sU16[(s * 256 + 4 * l) ^ ((s & 7) << 3)] = h;
    }
  };

  auto pass = [&]() {
    f32x4 vacc = {0.f, 0.f, 0.f, 0.f};
    const int nr = l & 15;
    const int grp = l >> 4;
    {
      float4 pre[4];
      #pragma unroll
      for (int k = 0; k < 4; ++k) pre[k] = g4[(w + 16 * k) * 64 + l];
      stage(pre);
    }
    __syncthreads();
    for (int chunk = 0; chunk < 8; ++chunk) {
      float4 nxt[4];
      if (chunk < 7) {
        #pragma unroll
        for (int k = 0; k < 4; ++k)
          nxt[k] = g4[((chunk + 1) * 64 + w + 16 * k) * 64 + l];
      }
      if (w < 4) {
        f32x4 y = {0.f, 0.f, 0.f, 0.f};
        const int arow = 16 * w + nr;
        #pragma unroll
        for (int ks = 0; ks < 8; ++ks) {
          bf16x8 a = *(const bf16x8*)&sU16[(arow * 256 + ks * 32 + grp * 8) ^ ((arow & 7) << 3)];
          bf16x8 bw = *(const bf16x8*)&sWt16[(nr * 256 + ks * 32 + grp * 8) ^ ((nr & 7) << 3)];
          y = __builtin_amdgcn_mfma_f32_16x16x32_bf16(a, bw, y, 0, 0, 0);
        }
        float e0 = __expf(y[0]), e1 = __expf(y[1]), e2 = __expf(y[2]), e3 = __expf(y[3]);
        float s0 = e0, s1 = e1, s2 = e2, s3 = e3;
        #pragma unroll
        for (int off = 1; off < 16; off <<= 1) {
          s0 += __shfl_xor(s0, off); s1 += __shfl_xor(s1, off);
          s2 += __shfl_xor(s2, off); s3 += __shfl_xor(s3, off);
        }
        u16x4 cw;
        cw[0] = f2bf(e0 / s0); cw[1] = f2bf(e1 / s1);
        cw[2] = f2bf(e2 / s2); cw[3] = f2bf(e3 / s3);
        *(u16x4*)&sCT16[(nr * 64 + 16 * w + 4 * grp) ^ ((nr & 7) << 3)] = cw;
      }
      __syncthreads();
      {
        const int icol = 16 * w + nr;
        #pragma unroll
        for (int ks = 0; ks < 2; ++ks) {
          bf16x8 a = *(const bf16x8*)&sCT16[(nr * 64 + ks * 32 + grp * 8) ^ ((nr & 7) << 3)];
          bf16x8 bb;
          const int s0b = ks * 32 + grp * 8;
          #pragma unroll
          for (int j = 0; j < 8; ++j) {
            unsigned short v = sU16[((s0b + j) * 256 + icol) ^ (j << 3)];
            bb[j] = __builtin_bit_cast(__bf16, v);
          }
          vacc = __builtin_amdgcn_mfma_f32_16x16x32_bf16(a, bb, vacc, 0, 0, 0);
        }
      }
      __syncthreads();
      if (chunk < 7) stage(nxt);
      __syncthreads();
    }
    #pragma unroll
    for (int r = 0; r < 4; ++r) sV[(grp * 4 + r) * 256 + 16 * w + nr] = vacc[r];
    __syncthreads();
  };

  outCompute(0);
  wtCompute();
  pass();
  outCompute(1);
  wtCompute();
  pass();
  outCompute(1);

  if (tid < 512) outp[(size_t)b * 512 + tid] = sOut[tid];
}

// ---------------------------------------------------------------- launch
extern "C" void kernel_launch(void* const* d_in, const int* in_sizes, int n_in,
                              void* d_out, int out_size, void* d_ws, size_t ws_size,
                              hipStream_t stream) {
  const float* U = (const float*)d_in[0];
  const float* W = (const float*)d_in[1];
  float* out = (float*)d_out;

  const size_t WT_OFF = 0;                  // 2 MB  bf16 wt [256][16][256]
  const size_t CP_OFF = 2u * 1024 * 1024;   // 1 MB  cpart [1024][256]
  const size_t VP_OFF = 3u * 1024 * 1024;   // 16 MB vpart [1024][16][256]
  const size_t UB_OFF = 19u * 1024 * 1024;  // 64 MB Ub bf16 [256][512][256]
  const size_t NEED   = UB_OFF + 64u * 1024 * 1024;

  if (ws_size < NEED) {
    caps_fused<<<dim3(256), dim3(1024), 0, stream>>>(U, W, out);
    return;
  }
  unsigned short* wt = (unsigned short*)((char*)d_ws + WT_OFF);
  float* cpart = (float*)((char*)d_ws + CP_OFF);
  float* vpart = (float*)((char*)d_ws + VP_OFF);
  unsigned short* Ub = (unsigned short*)((char*)d_ws + UB_OFF);

  hipFuncSetAttribute(reinterpret_cast<const void*>(k_pass),
                      hipFuncAttributeMaxDynamicSharedMemorySize, 77824);

  k_cvt<<<dim3(4, 256), 256, 0, stream>>>(U, cpart, Ub);
  k_route<<<256, 512, 0, stream>>>(W, cpart, wt, out, 0, 0);
  k_pass<<<dim3(4, 256), 512, 77824, stream>>>(Ub, wt, vpart);
  k_route<<<256, 512, 0, stream>>>(W, vpart, wt, out, 1, 0);
  k_pass<<<dim3(4, 256), 512, 77824, stream>>>(Ub, wt, vpart);
  k_route<<<256, 512, 0, stream>>>(W, vpart, wt, out, 1, 1);
}

// Round 8
// 296.935 us; speedup vs baseline: 1.0629x; 1.0192x over previous
//
#include <hip/hip_runtime.h>

// Capsule routing, 3-dispatch fused pipeline (round 8).
//   B=256, S=512, D=256, NC=16, DC=32, ROUTINGS=3
//   k_cvt_route: U fp32 -> Ub bf16 + colsum + out1 + wt1      (1 pass over U)
//   k_main(x2):  per batch: 4x128-row chunks (dbuf LDS), GEMM1 MFMA +
//                softmax_n + GEMM2 MFMA (V in regs), then route epilogue
//                (out, wt) in-block. Final call writes d_out.
// V never leaves the block (no vpart); wt is the only inter-kernel state
// (2 MB). Squash is scale-invariant so colsum/softmax uniform scales drop.

#define DIN   256
#define OC    512
#define SROWS 512

typedef __attribute__((ext_vector_type(8))) __bf16 bf16x8;
typedef __attribute__((ext_vector_type(4))) float f32x4;
typedef __attribute__((ext_vector_type(4))) unsigned short u16x4;

__device__ __forceinline__ unsigned short f2bf(float f) {
  unsigned u = __float_as_uint(f);
  u += 0x7FFFu + ((u >> 16) & 1u);   // RNE
  return (unsigned short)(u >> 16);
}

#define SWZ(r) ((((r) ^ ((r) >> 3)) & 7) << 3)

// ------------------------------------------------------------ k_cvt_route
// One block per batch. Read U[b] (512KB fp32), emit bf16 copy, colsum,
// out1 = squash(colsum @ W_n), wt1[n][i] = sum_d W[i][n*32+d]*out1[n*32+d].
__global__ __launch_bounds__(512) void k_cvt_route(
    const float* __restrict__ Uall, const float* __restrict__ W,
    unsigned short* __restrict__ Ub, unsigned short* __restrict__ wt)
{
  __shared__ float sA[8][256];
  __shared__ float sCS[256];
  __shared__ float sOut[512];
  const int b = blockIdx.x;
  const int tid = threadIdx.x;
  const int c4 = tid & 63, r0 = tid >> 6;   // r0 0..7
  const float4* g4 = (const float4*)(Uall + (size_t)b * (SROWS * DIN));
  unsigned short* ub = Ub + (size_t)b * (SROWS * DIN);

  float4 a = {0.f, 0.f, 0.f, 0.f};
  #pragma unroll 8
  for (int k = 0; k < 64; ++k) {
    const int row = r0 + 8 * k;
    float4 v = g4[row * 64 + c4];
    u16x4 h;
    h[0] = f2bf(v.x); h[1] = f2bf(v.y); h[2] = f2bf(v.z); h[3] = f2bf(v.w);
    *(u16x4*)&ub[(size_t)row * 256 + 4 * c4] = h;
    a.x += v.x; a.y += v.y; a.z += v.z; a.w += v.w;
  }
  *(float4*)&sA[r0][4 * c4] = a;
  __syncthreads();
  if (tid < 64) {
    float4 s = {0.f, 0.f, 0.f, 0.f};
    #pragma unroll
    for (int q = 0; q < 8; ++q) {
      float4 v = *(float4*)&sA[q][4 * tid];
      s.x += v.x; s.y += v.y; s.z += v.z; s.w += v.w;
    }
    *(float4*)&sCS[4 * tid] = s;
  }
  __syncthreads();

  // out1: p[c] = sum_i cs[i] * W[i][c]; squash per capsule (32 lanes)
  {
    const int c = tid;
    float p0 = 0.f, p1 = 0.f, p2 = 0.f, p3 = 0.f;
    #pragma unroll 4
    for (int i = 0; i < 256; i += 4) {
      p0 = fmaf(W[(size_t)(i + 0) * OC + c], sCS[i + 0], p0);
      p1 = fmaf(W[(size_t)(i + 1) * OC + c], sCS[i + 1], p1);
      p2 = fmaf(W[(size_t)(i + 2) * OC + c], sCS[i + 2], p2);
      p3 = fmaf(W[(size_t)(i + 3) * OC + c], sCS[i + 3], p3);
    }
    float p = (p0 + p1) + (p2 + p3);
    float sq = p * p;
    #pragma unroll
    for (int off = 1; off < 32; off <<= 1) sq += __shfl_xor(sq, off);
    sOut[c] = p * rsqrtf(sq + 1e-7f);
  }
  __syncthreads();

  // wt1 -> global (bf16)
  {
    const int f4i = tid & 127, rr = tid >> 7;
    const int n = f4i >> 3;
    const float4 ov = *(const float4*)&sOut[4 * f4i];
    #pragma unroll 4
    for (int it = 0; it < 64; ++it) {
      const int i = it * 4 + rr;
      const float4 wv = *(const float4*)&W[(size_t)i * OC + 4 * f4i];
      float p = wv.x * ov.x + wv.y * ov.y + wv.z * ov.z + wv.w * ov.w;
      p += __shfl_xor(p, 1);
      p += __shfl_xor(p, 2);
      p += __shfl_xor(p, 4);
      if ((tid & 7) == 0)
        wt[(size_t)b * 4096 + n * 256 + i] = f2bf(p);
    }
  }
}

// ---------------------------------------------------------------- k_main
// One block per batch. Dynamic LDS 143360 B:
//   sU0 @0      [128][256] ushort swz (64KB)   \ double buffer
//   sU1 @65536  [128][256] ushort swz (64KB)   /
//   sWt @131072 [16][256]  ushort swz (8KB)
//   sCT @139264 [16][128]  ushort swz (4KB)
// Route-phase aliases inside sU0: sV[16][256] f32 @0 (16KB),
//   sP[2][512] f32 @16384 (4KB), sOut[512] f32 @20480 (2KB).
__global__ __launch_bounds__(512, 1) void k_main(
    const unsigned short* __restrict__ Ub, const float* __restrict__ W,
    unsigned short* __restrict__ wt, float* __restrict__ outF, int final_)
{
  extern __shared__ char smem[];
  unsigned short* sU0 = (unsigned short*)smem;
  unsigned short* sU1 = (unsigned short*)(smem + 65536);
  unsigned short* sWt = (unsigned short*)(smem + 131072);
  unsigned short* sCT = (unsigned short*)(smem + 139264);
  float* sV   = (float*)smem;
  float* sP   = (float*)(smem + 16384);
  float* sOut = (float*)(smem + 20480);

  const int b = blockIdx.x;
  const int tid = threadIdx.x;
  const int w = tid >> 6, l = tid & 63;
  const int nr = l & 15, g = l >> 4;
  const unsigned short* ub = Ub + (size_t)b * (SROWS * DIN);

  // wt (slice b) -> sWt: 512 thr x uint4 = 16 rows x 256 cols
  {
    const int n = tid >> 5, i0 = (tid & 31) * 8;
    const uint4 wv = *(const uint4*)&wt[(size_t)b * 4096 + n * 256 + i0];
    *(uint4*)&sWt[(n * 256 + i0) ^ SWZ(n)] = wv;
  }

  const int col8 = (tid & 31) * 8;
  const int sr0 = tid >> 5;   // 0..15
  auto stageTo = [&](unsigned short* dst, int R0) {
    #pragma unroll
    for (int k = 0; k < 8; ++k) {
      const int row = sr0 + 16 * k;   // 0..127
      const uint4 v = *(const uint4*)&ub[(size_t)(R0 + row) * 256 + col8];
      *(uint4*)&dst[(row * 256 + col8) ^ SWZ(row)] = v;
    }
  };
  stageTo(sU0, 0);
  __syncthreads();

  f32x4 v0acc = {0.f, 0.f, 0.f, 0.f}, v1acc = {0.f, 0.f, 0.f, 0.f};
  const int icol0 = 32 * w + nr, icol1 = icol0 + 16;

  for (int c = 0; c < 4; ++c) {
    unsigned short* cur = (c & 1) ? sU1 : sU0;
    unsigned short* nxt = (c & 1) ? sU0 : sU1;
    if (c < 3) stageTo(nxt, (c + 1) * 128);   // overlaps GEMM1 on cur

    // GEMM1: Y[16 rows (16w..)][16 n]; softmax over n; C^T -> sCT
    {
      f32x4 y = {0.f, 0.f, 0.f, 0.f};
      const int arow = 16 * w + nr;
      #pragma unroll
      for (int ks = 0; ks < 8; ++ks) {
        bf16x8 a  = *(const bf16x8*)&cur[(arow * 256 + ks * 32 + g * 8) ^ SWZ(arow)];
        bf16x8 bw = *(const bf16x8*)&sWt[(nr * 256 + ks * 32 + g * 8) ^ SWZ(nr)];
        y = __builtin_amdgcn_mfma_f32_16x16x32_bf16(a, bw, y, 0, 0, 0);
      }
      float e0 = __expf(y[0]), e1 = __expf(y[1]), e2 = __expf(y[2]), e3 = __expf(y[3]);
      float s0 = e0, s1 = e1, s2 = e2, s3 = e3;
      #pragma unroll
      for (int off = 1; off < 16; off <<= 1) {
        s0 += __shfl_xor(s0, off); s1 += __shfl_xor(s1, off);
        s2 += __shfl_xor(s2, off); s3 += __shfl_xor(s3, off);
      }
      u16x4 cw;
      cw[0] = f2bf(e0 / s0); cw[1] = f2bf(e1 / s1);
      cw[2] = f2bf(e2 / s2); cw[3] = f2bf(e3 / s3);
      *(u16x4*)&sCT[(nr * 128 + 16 * w + 4 * g) ^ SWZ(nr)] = cw;
    }
    __syncthreads();

    // GEMM2: V[16n][256i] += C^T . chunk; wave w covers icol0/icol1
    {
      #pragma unroll
      for (int ks = 0; ks < 4; ++ks) {
        bf16x8 a = *(const bf16x8*)&sCT[(nr * 128 + ks * 32 + g * 8) ^ SWZ(nr)];
        bf16x8 b0, b1;
        #pragma unroll
        for (int j = 0; j < 8; ++j) {
          const int s = ks * 32 + g * 8 + j;
          b0[j] = __builtin_bit_cast(__bf16, cur[(s * 256 + icol0) ^ SWZ(s)]);
          b1[j] = __builtin_bit_cast(__bf16, cur[(s * 256 + icol1) ^ SWZ(s)]);
        }
        v0acc = __builtin_amdgcn_mfma_f32_16x16x32_bf16(a, b0, v0acc, 0, 0, 0);
        v1acc = __builtin_amdgcn_mfma_f32_16x16x32_bf16(a, b1, v1acc, 0, 0, 0);
      }
    }
    __syncthreads();   // cur free for next-next stage; CT free for rewrite
  }

  // V -> sV (aliases sU0; last chunk used sU1, and barrier above passed)
  #pragma unroll
  for (int r = 0; r < 4; ++r) {
    const int n = 4 * g + r;
    sV[n * 256 + icol0] = v0acc[r];
    sV[n * 256 + icol1] = v1acc[r];
  }
  __syncthreads();

  // route B: p[c] = sum_i V[n][i] * W[i][c]  (i split over 2 halves)
  {
    const int pair = tid & 255, half = tid >> 8;
    const int c0 = pair * 2, n = c0 >> 5;
    float p0 = 0.f, p1 = 0.f;
    const int i0h = half * 128;
    #pragma unroll 8
    for (int i = i0h; i < i0h + 128; ++i) {
      const float2 wv = *(const float2*)&W[(size_t)i * OC + c0];
      const float x = sV[n * 256 + i];
      p0 = fmaf(wv.x, x, p0);
      p1 = fmaf(wv.y, x, p1);
    }
    sP[half * 512 + c0] = p0; sP[half * 512 + c0 + 1] = p1;
  }
  __syncthreads();

  // route C: squash
  {
    const float p = sP[tid] + sP[512 + tid];
    float sq = p * p;
    #pragma unroll
    for (int off = 1; off < 32; off <<= 1) sq += __shfl_xor(sq, off);
    const float o = p * rsqrtf(sq + 1e-7f);
    if (final_) { outF[(size_t)b * 512 + tid] = o; return; }
    sOut[tid] = o;
  }
  __syncthreads();

  // route D: wt (slice b) rewrite — safe: sWt snapshot taken before
  {
    const int f4i = tid & 127, rr = tid >> 7;
    const int n = f4i >> 3;
    const float4 ov = *(const float4*)&sOut[4 * f4i];
    #pragma unroll 4
    for (int it = 0; it < 64; ++it) {
      const int i = it * 4 + rr;
      const float4 wv = *(const float4*)&W[(size_t)i * OC + 4 * f4i];
      float p = wv.x * ov.x + wv.y * ov.y + wv.z * ov.z + wv.w * ov.w;
      p += __shfl_xor(p, 1);
      p += __shfl_xor(p, 2);
      p += __shfl_xor(p, 4);
      if ((tid & 7) == 0)
        wt[(size_t)b * 4096 + n * 256 + i] = f2bf(p);
    }
  }
}

// ------------------------------------------------------- fallback (round 1)
__global__ __launch_bounds__(1024) void caps_fused(
    const float* __restrict__ Uall, const float* __restrict__ Wg,
    float* __restrict__ outp)
{
  __shared__ __align__(16) unsigned short sU16[64 * 256];
  __shared__ __align__(16) unsigned short sWt16[16 * 256];
  __shared__ __align__(16) unsigned short sCT16[16 * 64];
  __shared__ __align__(16) float sV[16 * 256];
  __shared__ __align__(16) float sOut[512];
  float* sSS = (float*)sCT16;

  const int tid = threadIdx.x;
  const int w = tid >> 6, l = tid & 63;
  const int b = blockIdx.x;
  const float* U = Uall + (size_t)b * (SROWS * DIN);
  const float4* g4 = (const float4*)U;

  {
    float4 a = make_float4(0.f, 0.f, 0.f, 0.f);
    const int base = (w * 32) * 64 + l;
    #pragma unroll 8
    for (int r = 0; r < 32; ++r) {
      float4 v = g4[base + r * 64];
      a.x += v.x; a.y += v.y; a.z += v.z; a.w += v.w;
    }
    *(float4*)&sV[w * 256 + 4 * l] = a;
  }
  __syncthreads();
  if (tid < 256) {
    float s = 0.f;
    #pragma unroll
    for (int q = 0; q < 16; ++q) s += sV[q * 256 + tid];
    sSS[tid] = s * (1.0f / 16.0f);
  }
  __syncthreads();

  auto outCompute = [&](int mode) {
    if (tid < 512) {
      const int c = tid, n = c >> 5;
      float p0 = 0.f, p1 = 0.f, p2 = 0.f, p3 = 0.f;
      #pragma unroll 4
      for (int i = 0; i < 256; i += 4) {
        float x0 = mode ? sV[n * 256 + i + 0] : sSS[i + 0];
        float x1 = mode ? sV[n * 256 + i + 1] : sSS[i + 1];
        float x2 = mode ? sV[n * 256 + i + 2] : sSS[i + 2];
        float x3 = mode ? sV[n * 256 + i + 3] : sSS[i + 3];
        p0 = fmaf(Wg[(i + 0) * OC + c], x0, p0);
        p1 = fmaf(Wg[(i + 1) * OC + c], x1, p1);
        p2 = fmaf(Wg[(i + 2) * OC + c], x2, p2);
        p3 = fmaf(Wg[(i + 3) * OC + c], x3, p3);
      }
      float p = (p0 + p1) + (p2 + p3);
      float sq = p * p;
      #pragma unroll
      for (int off = 1; off < 32; off <<= 1) sq += __shfl_xor(sq, off);
      sOut[c] = p * rsqrtf(sq + 1e-7f);
    }
    __syncthreads();
  };

  auto wtCompute = [&]() {
    const int f4 = tid & 127;
    const int rr = tid >> 7;
    const float4 ov = *(const float4*)&sOut[4 * f4];
    #pragma unroll 4
    for (int it = 0; it < 32; ++it) {
      const int i = it * 8 + rr;
      const float4 wv = *(const float4*)&Wg[i * OC + 4 * f4];
      float p = wv.x * ov.x + wv.y * ov.y + wv.z * ov.z + wv.w * ov.w;
      p += __shfl_xor(p, 1);
      p += __shfl_xor(p, 2);
      p += __shfl_xor(p, 4);
      if ((f4 & 7) == 0) {
        const int n = f4 >> 3;
        sWt16[(n * 256 + i) ^ ((n & 7) << 3)] = f2bf(p);
      }
    }
    __syncthreads();
  };

  auto stage = [&](const float4* pre) {
    #pragma unroll
    for (int k = 0; k < 4; ++k) {
      const int s = w + 16 * k;
      u16x4 h;
      h[0] = f2bf(pre[k].x); h[1] = f2bf(pre[k].y);
      h[2] = f2bf(pre[k].z); h[3] = f2bf(pre[k].w);
      *(u16x4*)&sU16[(s * 256 + 4 * l) ^ ((s & 7) << 3)] = h;
    }
  };

  auto pass = [&]() {
    f32x4 vacc = {0.f, 0.f, 0.f, 0.f};
    const int nr = l & 15;
    const int grp = l >> 4;
    {
      float4 pre[4];
      #pragma unroll
      for (int k = 0; k < 4; ++k) pre[k] = g4[(w + 16 * k) * 64 + l];
      stage(pre);
    }
    __syncthreads();
    for (int chunk = 0; chunk < 8; ++chunk) {
      float4 nxt[4];
      if (chunk < 7) {
        #pragma unroll
        for (int k = 0; k < 4; ++k)
          nxt[k] = g4[((chunk + 1) * 64 + w + 16 * k) * 64 + l];
      }
      if (w < 4) {
        f32x4 y = {0.f, 0.f, 0.f, 0.f};
        const int arow = 16 * w + nr;
        #pragma unroll
        for (int ks = 0; ks < 8; ++ks) {
          bf16x8 a = *(const bf16x8*)&sU16[(arow * 256 + ks * 32 + grp * 8) ^ ((arow & 7) << 3)];
          bf16x8 bw = *(const bf16x8*)&sWt16[(nr * 256 + ks * 32 + grp * 8) ^ ((nr & 7) << 3)];
          y = __builtin_amdgcn_mfma_f32_16x16x32_bf16(a, bw, y, 0, 0, 0);
        }
        float e0 = __expf(y[0]), e1 = __expf(y[1]), e2 = __expf(y[2]), e3 = __expf(y[3]);
        float s0 = e0, s1 = e1, s2 = e2, s3 = e3;
        #pragma unroll
        for (int off = 1; off < 16; off <<= 1) {
          s0 += __shfl_xor(s0, off); s1 += __shfl_xor(s1, off);
          s2 += __shfl_xor(s2, off); s3 += __shfl_xor(s3, off);
        }
        u16x4 cw;
        cw[0] = f2bf(e0 / s0); cw[1] = f2bf(e1 / s1);
        cw[2] = f2bf(e2 / s2); cw[3] = f2bf(e3 / s3);
        *(u16x4*)&sCT16[(nr * 64 + 16 * w + 4 * grp) ^ ((nr & 7) << 3)] = cw;
      }
      __syncthreads();
      {
        const int icol = 16 * w + nr;
        #pragma unroll
        for (int ks = 0; ks < 2; ++ks) {
          bf16x8 a = *(const bf16x8*)&sCT16[(nr * 64 + ks * 32 + grp * 8) ^ ((nr & 7) << 3)];
          bf16x8 bb;
          const int s0b = ks * 32 + grp * 8;
          #pragma unroll
          for (int j = 0; j < 8; ++j) {
            unsigned short v = sU16[((s0b + j) * 256 + icol) ^ (j << 3)];
            bb[j] = __builtin_bit_cast(__bf16, v);
          }
          vacc = __builtin_amdgcn_mfma_f32_16x16x32_bf16(a, bb, vacc, 0, 0, 0);
        }
      }
      __syncthreads();
      if (chunk < 7) stage(nxt);
      __syncthreads();
    }
    #pragma unroll
    for (int r = 0; r < 4; ++r) sV[(grp * 4 + r) * 256 + 16 * w + nr] = vacc[r];
    __syncthreads();
  };

  outCompute(0);
  wtCompute();
  pass();
  outCompute(1);
  wtCompute();
  pass();
  outCompute(1);

  if (tid < 512) outp[(size_t)b * 512 + tid] = sOut[tid];
}

// ---------------------------------------------------------------- launch
extern "C" void kernel_launch(void* const* d_in, const int* in_sizes, int n_in,
                              void* d_out, int out_size, void* d_ws, size_t ws_size,
                              hipStream_t stream) {
  const float* U = (const float*)d_in[0];
  const float* W = (const float*)d_in[1];
  float* out = (float*)d_out;

  const size_t WT_OFF = 0;                 // 2 MB  bf16 wt [256][16][256]
  const size_t UB_OFF = 2u * 1024 * 1024;  // 64 MB Ub bf16 [256][512][256]
  const size_t NEED   = UB_OFF + 64u * 1024 * 1024;

  if (ws_size < NEED) {
    caps_fused<<<dim3(256), dim3(1024), 0, stream>>>(U, W, out);
    return;
  }
  unsigned short* wt = (unsigned short*)((char*)d_ws + WT_OFF);
  unsigned short* Ub = (unsigned short*)((char*)d_ws + UB_OFF);

  hipFuncSetAttribute(reinterpret_cast<const void*>(k_main),
                      hipFuncAttributeMaxDynamicSharedMemorySize, 143360);

  k_cvt_route<<<256, 512, 0, stream>>>(U, W, Ub, wt);
  k_main<<<256, 512, 143360, stream>>>(Ub, W, wt, out, 0);
  k_main<<<256, 512, 143360, stream>>>(Ub, W, wt, out, 1);
}